// Round 8
// baseline (222.228 us; speedup 1.0000x reference)
//
#include <hip/hip_runtime.h>

// ACE symmetrizer, fused persistent kernel.
// b[r,f,n] = sum_m cg[r,m] * A[f,m,n] for 5 (A, CG0, CG1) groups.
// Memory-bound: ~500MB read + 537MB write -> ~165us floor at 6.3 TB/s.
//
// Round-8 vs round-7 (207us, 4 waves/SIMD):
//  - PERSISTENT blocks: 2048 blocks x 8 tiles each (tile = op, f, 256-n-quarter,
//    one float per thread). Kills the per-block s_endpgm store-drain stall.
//  - DUAL ACC BANKS: tiles alternate accA/accB. Bank-A stores only need to
//    complete when tile k+2 re-zeroes bank A -> one full tile of compute
//    overlaps the store latency (was: dead wait at every block end).
//  - acc = 32 scalar floats per bank; ~90 VGPR total -> 4 waves/SIMD, no spill.

#define NN 1024

// output float offsets (return order: b0 x5 then b1 x5)
#define O0_0 0UL
#define O0_1 8388608UL
#define O0_2 16777216UL
#define O0_3 25165824UL
#define O0_4 29360128UL
#define O1_0 33554432UL
#define O1_1 58720256UL
#define O1_2 83886080UL
#define O1_3 109051904UL
#define O1_4 121634816UL

// padded cgT float offsets in ws: 32*MP per op, MP = {12,28,52,28,48}
#define WP_0 0
#define WP_1 384
#define WP_2 1280
#define WP_3 2944
#define WP_4 3840
#define WP_TOT 5376

#define GRID 2048   // persistent blocks; 16384 tiles / 2048 = 8 tiles each

__global__ __launch_bounds__(256)
void cg_transpose(const float* __restrict__ c00, const float* __restrict__ c01,
                  const float* __restrict__ c02, const float* __restrict__ c03,
                  const float* __restrict__ c04,
                  const float* __restrict__ c10, const float* __restrict__ c11,
                  const float* __restrict__ c12, const float* __restrict__ c13,
                  const float* __restrict__ c14,
                  float* __restrict__ w)
{
    int t = blockIdx.x * 256 + threadIdx.x;
    if (t >= WP_TOT) return;
    int M, off; const float* g0; const float* g1;
    if      (t < WP_1) { M = 9;  off = WP_0; g0 = c00; g1 = c10; }
    else if (t < WP_2) { M = 25; off = WP_1; g0 = c01; g1 = c11; }
    else if (t < WP_3) { M = 49; off = WP_2; g0 = c02; g1 = c12; }
    else if (t < WP_4) { M = 27; off = WP_3; g0 = c03; g1 = c13; }
    else               { M = 45; off = WP_4; g0 = c04; g1 = c14; }
    int loc = t - off;
    int m = loc >> 5, r = loc & 31;
    float v = 0.f;
    if (m < M) v = (r < 8) ? g0[r * M + m] : g1[(r - 8) * M + m];
    w[t] = v;
}

// One tile: 32 r-rows x 1 n-element per thread, into the given acc bank.
template<int M, int MP>
__device__ __forceinline__ void tile_op(const float* __restrict__ Af,  // A + f*M*NN + n0
                                        const float* __restrict__ cg,  // cgT + WP_op
                                        float* __restrict__ p0,        // out0 + f*NN + n0
                                        float* __restrict__ p1,        // out1 + f*NN + n0
                                        size_t stride,                 // F*NN
                                        float (&acc)[32])
{
    float buf[4];
#pragma unroll
    for (int i = 0; i < 4; ++i) {
        const int mi = (i < M) ? i : (M - 1);
        buf[i] = __builtin_nontemporal_load(Af + (size_t)mi * NN);
    }

    // overwrite of acc waits (vmcnt) for this bank's stores from 2 tiles ago:
    // a full tile of slack -> store latency hidden.
#pragma unroll
    for (int r = 0; r < 32; ++r) acc[r] = 0.f;

#pragma unroll 1
    for (int m = 0; m < MP; m += 4) {
#pragma unroll
        for (int i = 0; i < 4; ++i) {
            const float cur = buf[i];
            int nm = m + 4 + i;
            nm = (nm < M) ? nm : (M - 1);            // clamped prefetch
            buf[i] = __builtin_nontemporal_load(Af + (size_t)nm * NN);
            const float* c = cg + (size_t)(m + i) * 32;   // uniform -> s_load x2
#pragma unroll
            for (int r = 0; r < 32; ++r)
                acc[r] = fmaf(c[r], cur, acc[r]);
        }
    }

#pragma unroll
    for (int r = 0; r < 8; ++r)
        __builtin_nontemporal_store(acc[r], p0 + (size_t)r * stride);
#pragma unroll
    for (int r = 0; r < 24; ++r)
        __builtin_nontemporal_store(acc[8 + r], p1 + (size_t)r * stride);
}

// Decode tile index -> (op, f, n-quarter) and run it. Heavy ops first.
__device__ __forceinline__ void do_tile(int t, int tid,
                                        const float* __restrict__ A0,
                                        const float* __restrict__ A1,
                                        const float* __restrict__ A2,
                                        const float* __restrict__ A3,
                                        const float* __restrict__ A4,
                                        const float* __restrict__ cgT,
                                        float* __restrict__ out,
                                        float (&acc)[32])
{
    if (t < 4096) {                                   // M=49, F=1024
        const size_t f = t >> 2;
        const int n0 = ((t & 3) << 8) + tid;
        tile_op<49, 52>(A2 + f * 49 * NN + n0, cgT + WP_2,
                        out + O0_2 + f * NN + n0, out + O1_2 + f * NN + n0,
                        (size_t)1024 * NN, acc);
    } else if (t < 6144) {                            // M=45, F=512
        const int loc = t - 4096;
        const size_t f = loc >> 2;
        const int n0 = ((loc & 3) << 8) + tid;
        tile_op<45, 48>(A4 + f * 45 * NN + n0, cgT + WP_4,
                        out + O0_4 + f * NN + n0, out + O1_4 + f * NN + n0,
                        (size_t)512 * NN, acc);
    } else if (t < 10240) {                           // M=25, F=1024
        const int loc = t - 6144;
        const size_t f = loc >> 2;
        const int n0 = ((loc & 3) << 8) + tid;
        tile_op<25, 28>(A1 + f * 25 * NN + n0, cgT + WP_1,
                        out + O0_1 + f * NN + n0, out + O1_1 + f * NN + n0,
                        (size_t)1024 * NN, acc);
    } else if (t < 12288) {                           // M=27, F=512
        const int loc = t - 10240;
        const size_t f = loc >> 2;
        const int n0 = ((loc & 3) << 8) + tid;
        tile_op<27, 28>(A3 + f * 27 * NN + n0, cgT + WP_3,
                        out + O0_3 + f * NN + n0, out + O1_3 + f * NN + n0,
                        (size_t)512 * NN, acc);
    } else {                                          // M=9, F=1024
        const int loc = t - 12288;
        const size_t f = loc >> 2;
        const int n0 = ((loc & 3) << 8) + tid;
        tile_op<9, 12>(A0 + f * 9 * NN + n0, cgT + WP_0,
                       out + O0_0 + f * NN + n0, out + O1_0 + f * NN + n0,
                       (size_t)1024 * NN, acc);
    }
}

__global__ __launch_bounds__(256)
void ace_sym_all(const float* __restrict__ A0, const float* __restrict__ A1,
                 const float* __restrict__ A2, const float* __restrict__ A3,
                 const float* __restrict__ A4,
                 const float* __restrict__ cgT, float* __restrict__ out)
{
    const int tid = (int)threadIdx.x;
    float accA[32], accB[32];

    int t = (int)blockIdx.x;
#pragma unroll 1
    for (int k = 0; k < 4; ++k) {
        do_tile(t, tid, A0, A1, A2, A3, A4, cgT, out, accA);
        t += GRID;
        do_tile(t, tid, A0, A1, A2, A3, A4, cgT, out, accB);
        t += GRID;
    }
}

extern "C" void kernel_launch(void* const* d_in, const int* in_sizes, int n_in,
                              void* d_out, int out_size, void* d_ws, size_t ws_size,
                              hipStream_t stream)
{
    const float* A0 = (const float*)d_in[0];
    const float* A1 = (const float*)d_in[1];
    const float* A2 = (const float*)d_in[2];
    const float* A3 = (const float*)d_in[3];
    const float* A4 = (const float*)d_in[4];

    float* wsT = (float*)d_ws;

    hipLaunchKernelGGL(cg_transpose, dim3((WP_TOT + 255) / 256), dim3(256), 0, stream,
                       (const float*)d_in[5], (const float*)d_in[6], (const float*)d_in[7],
                       (const float*)d_in[8], (const float*)d_in[9],
                       (const float*)d_in[10], (const float*)d_in[11], (const float*)d_in[12],
                       (const float*)d_in[13], (const float*)d_in[14], wsT);

    hipLaunchKernelGGL(ace_sym_all, dim3(GRID), dim3(256), 0, stream,
                       A0, A1, A2, A3, A4, (const float*)wsT, (float*)d_out);
}

// Round 9
// 211.291 us; speedup vs baseline: 1.0518x; 1.0518x over previous
//
#include <hip/hip_runtime.h>

// ACE symmetrizer, fused: b[r,f,n] = sum_m cg[r,m] * A[f,m,n] for 5 (A, CG0, CG1)
// groups in ONE kernel. Memory-bound: ~500MB read + 537MB write -> ~165us floor.
//
// Round-9 vs round-7 (207us, 4 waves/SIMD):
//  - 512-thread blocks, r-split halves: tid<256 -> r0..15, tid>=256 -> r16..31.
//    acc[16] x f32x2 = 32 VGPR, buf 8, addr ~15 -> ~55 live, cap 64 via
//    __launch_bounds__(512,8) -> 8 waves/SIMD (2x round-7's occupancy).
//  - half = readfirstlane(tid>>8): compiler-visible WAVE-UNIFORM -> CG pointer
//    stays SGPR -> s_load_dwordx16 (round-5's silent failure mode fixed; its
//    other failure, spills, is avoided since live state 55 < 64 cap).
//  - A loads cached (sibling half hits L1/MSHR on same CU -> no extra HBM);
//    stores nontemporal.

typedef float f32x2 __attribute__((ext_vector_type(2)));

#define NN 1024

// output float offsets (return order: b0 x5 then b1 x5)
#define O0_0 0UL
#define O0_1 8388608UL
#define O0_2 16777216UL
#define O0_3 25165824UL
#define O0_4 29360128UL
#define O1_0 33554432UL
#define O1_1 58720256UL
#define O1_2 83886080UL
#define O1_3 109051904UL
#define O1_4 121634816UL

// padded cgT float offsets in ws: 32*MP per op, MP = {12,28,52,28,48}
#define WP_0 0
#define WP_1 384
#define WP_2 1280
#define WP_3 2944
#define WP_4 3840
#define WP_TOT 5376

__global__ __launch_bounds__(256)
void cg_transpose(const float* __restrict__ c00, const float* __restrict__ c01,
                  const float* __restrict__ c02, const float* __restrict__ c03,
                  const float* __restrict__ c04,
                  const float* __restrict__ c10, const float* __restrict__ c11,
                  const float* __restrict__ c12, const float* __restrict__ c13,
                  const float* __restrict__ c14,
                  float* __restrict__ w)
{
    int t = blockIdx.x * 256 + threadIdx.x;
    if (t >= WP_TOT) return;
    int M, off; const float* g0; const float* g1;
    if      (t < WP_1) { M = 9;  off = WP_0; g0 = c00; g1 = c10; }
    else if (t < WP_2) { M = 25; off = WP_1; g0 = c01; g1 = c11; }
    else if (t < WP_3) { M = 49; off = WP_2; g0 = c02; g1 = c12; }
    else if (t < WP_4) { M = 27; off = WP_3; g0 = c03; g1 = c13; }
    else               { M = 45; off = WP_4; g0 = c04; g1 = c14; }
    int loc = t - off;
    int m = loc >> 5, r = loc & 31;
    float v = 0.f;
    if (m < M) v = (r < 8) ? g0[r * M + m] : g1[(r - 8) * M + m];
    w[t] = v;
}

// One r-half (16 rows) of one (op, f, n-512-range).
// cgh = cgT + WP_op + half*16 (uniform); Af = A + f*M*NN + n0.
template<int M, int MP>
__device__ __forceinline__ void run_half(const float* __restrict__ Af,
                                         const float* __restrict__ cgh,
                                         float* __restrict__ p0,
                                         float* __restrict__ p1,
                                         size_t stride, int half)
{
    const f32x2* ap = reinterpret_cast<const f32x2*>(Af);

    f32x2 buf[4];
#pragma unroll
    for (int i = 0; i < 4; ++i)
        buf[i] = ap[(size_t)i * (NN / 2)];           // cached: sibling half reuses

    f32x2 acc[16];
#pragma unroll
    for (int r = 0; r < 16; ++r) acc[r] = (f32x2)(0.f);

#pragma unroll 1
    for (int m = 0; m < MP; m += 4) {
#pragma unroll
        for (int i = 0; i < 4; ++i) {
            const f32x2 cur = buf[i];
            int nm = m + 4 + i;
            nm = (nm < M) ? nm : (M - 1);            // clamped prefetch (cache hit)
            buf[i] = ap[(size_t)nm * (NN / 2)];
            const float* c = cgh + (size_t)(m + i) * 32;  // uniform -> s_load_dwordx16
#pragma unroll
            for (int r = 0; r < 16; ++r) {
                const float cr = c[r];
                acc[r].x = fmaf(cr, cur.x, acc[r].x);
                acc[r].y = fmaf(cr, cur.y, acc[r].y);
            }
        }
    }

    if (half == 0) {
        // global r 0..15: rows 0..7 -> out0; rows 8..15 -> out1 rows 0..7
#pragma unroll
        for (int r = 0; r < 8; ++r)
            __builtin_nontemporal_store(acc[r], reinterpret_cast<f32x2*>(p0 + (size_t)r * stride));
#pragma unroll
        for (int r = 0; r < 8; ++r)
            __builtin_nontemporal_store(acc[8 + r], reinterpret_cast<f32x2*>(p1 + (size_t)r * stride));
    } else {
        // global r 16..31 -> out1 rows 8..23
#pragma unroll
        for (int r = 0; r < 16; ++r)
            __builtin_nontemporal_store(acc[r], reinterpret_cast<f32x2*>(p1 + (size_t)(8 + r) * stride));
    }
}

__global__ __launch_bounds__(512, 8)
void ace_sym_all(const float* __restrict__ A0, const float* __restrict__ A1,
                 const float* __restrict__ A2, const float* __restrict__ A3,
                 const float* __restrict__ A4,
                 const float* __restrict__ cgT, float* __restrict__ out)
{
    const int bid = blockIdx.x;
    const int tid = (int)threadIdx.x;
    // wave-uniform half (256 = 4-wave boundary); readfirstlane makes the
    // compiler SEE the uniformity -> CG pointer stays scalar (s_load path).
    const int half = __builtin_amdgcn_readfirstlane(tid >> 8);
    const int n0base = (tid & 255) * 2;

    // heavy-first: M=49 (F=1024), M=45 (512), M=25 (1024), M=27 (512), M=9 (1024)
    if (bid < 2048) {
        const size_t f = bid >> 1;
        const int n0 = ((bid & 1) << 9) + n0base;
        run_half<49, 52>(A2 + f * 49 * NN + n0, cgT + WP_2 + half * 16,
                         out + O0_2 + f * NN + n0, out + O1_2 + f * NN + n0,
                         (size_t)1024 * NN, half);
    } else if (bid < 3072) {
        const int loc = bid - 2048;
        const size_t f = loc >> 1;
        const int n0 = ((loc & 1) << 9) + n0base;
        run_half<45, 48>(A4 + f * 45 * NN + n0, cgT + WP_4 + half * 16,
                         out + O0_4 + f * NN + n0, out + O1_4 + f * NN + n0,
                         (size_t)512 * NN, half);
    } else if (bid < 5120) {
        const int loc = bid - 3072;
        const size_t f = loc >> 1;
        const int n0 = ((loc & 1) << 9) + n0base;
        run_half<25, 28>(A1 + f * 25 * NN + n0, cgT + WP_1 + half * 16,
                         out + O0_1 + f * NN + n0, out + O1_1 + f * NN + n0,
                         (size_t)1024 * NN, half);
    } else if (bid < 6144) {
        const int loc = bid - 5120;
        const size_t f = loc >> 1;
        const int n0 = ((loc & 1) << 9) + n0base;
        run_half<27, 28>(A3 + f * 27 * NN + n0, cgT + WP_3 + half * 16,
                         out + O0_3 + f * NN + n0, out + O1_3 + f * NN + n0,
                         (size_t)512 * NN, half);
    } else {
        const int loc = bid - 6144;
        const size_t f = loc >> 1;
        const int n0 = ((loc & 1) << 9) + n0base;
        run_half<9, 12>(A0 + f * 9 * NN + n0, cgT + WP_0 + half * 16,
                        out + O0_0 + f * NN + n0, out + O1_0 + f * NN + n0,
                        (size_t)1024 * NN, half);
    }
}

extern "C" void kernel_launch(void* const* d_in, const int* in_sizes, int n_in,
                              void* d_out, int out_size, void* d_ws, size_t ws_size,
                              hipStream_t stream)
{
    const float* A0 = (const float*)d_in[0];
    const float* A1 = (const float*)d_in[1];
    const float* A2 = (const float*)d_in[2];
    const float* A3 = (const float*)d_in[3];
    const float* A4 = (const float*)d_in[4];

    float* wsT = (float*)d_ws;

    hipLaunchKernelGGL(cg_transpose, dim3((WP_TOT + 255) / 256), dim3(256), 0, stream,
                       (const float*)d_in[5], (const float*)d_in[6], (const float*)d_in[7],
                       (const float*)d_in[8], (const float*)d_in[9],
                       (const float*)d_in[10], (const float*)d_in[11], (const float*)d_in[12],
                       (const float*)d_in[13], (const float*)d_in[14], wsT);

    hipLaunchKernelGGL(ace_sym_all, dim3(8192), dim3(512), 0, stream,
                       A0, A1, A2, A3, A4, (const float*)wsT, (float*)d_out);
}